// Round 6
// baseline (403.068 us; speedup 1.0000x reference)
//
#include <hip/hip_runtime.h>

#define BB 8
#define TT 4096
#define CC 512
#define NCHUNK 128
#define LCHUNK (TT / NCHUNK)   // 32
#define FLAG_MAGIC 0x1337BEEFu

typedef float floatx4 __attribute__((ext_vector_type(4)));

// Single-launch decoupled-lookback scan. Block (b,chunk):
//   1. stage x chunk in registers, local scan (zero init)
//   2. publish chunk-end state + release flag (distributed, uncontended)
//   3. spin-wait on predecessors' flags (one per lane, parallel)
//   4. prefix over predecessors' end states via A^LCHUNK
//   5. emit all LCHUNK steps from register-staged x (nontemporal stores)
__global__ __launch_bounds__(256, 4) void rec_lookback(const float* __restrict__ x,
                                                       const float* __restrict__ Ar,
                                                       const float* __restrict__ Ai,
                                                       const float* __restrict__ h0r,
                                                       const float* __restrict__ h0i,
                                                       float4* __restrict__ s_end,
                                                       unsigned int* __restrict__ flags,
                                                       float4* __restrict__ out) {
    const int tid   = threadIdx.x;            // channels 2*tid, 2*tid+1
    const int blk   = blockIdx.x;
    const int b     = blk / NCHUNK;
    const int chunk = blk % NCHUNK;
    const int t0    = chunk * LCHUNK;

    const float2 a_r = ((const float2*)Ar)[tid];
    const float2 a_i = ((const float2*)Ai)[tid];
    // Load h0 early (inputs immutable; read before any fence).
    const float2 h0rv = ((const float2*)(h0r + (size_t)b * CC))[tid];
    const float2 h0iv = ((const float2*)(h0i + (size_t)b * CC))[tid];

    const float2* xp = (const float2*)(x + (size_t)(b * TT + t0) * CC) + tid;

    // Stage this chunk's x: 32 x float2 (lands in VGPR/AGPR, no scratch - R5).
    float2 xs[LCHUNK];
#pragma unroll
    for (int t = 0; t < LCHUNK; ++t)
        xs[t] = xp[(size_t)t * (CC / 2)];

    // Local scan with zero init.
    float hr0 = 0.f, hi0 = 0.f, hr1 = 0.f, hi1 = 0.f;
#pragma unroll
    for (int t = 0; t < LCHUNK; ++t) {
        float2 xv = xs[t];
        float nr0 = fmaf(hr0, a_r.x, fmaf(-hi0, a_i.x, xv.x));
        float ni0 = fmaf(a_i.x, hr0, a_r.x * hi0);
        float nr1 = fmaf(hr1, a_r.y, fmaf(-hi1, a_i.y, xv.y));
        float ni1 = fmaf(a_i.y, hr1, a_r.y * hi1);
        hr0 = nr0; hi0 = ni0; hr1 = nr1; hi1 = ni1;
    }

    // Publish end state. Only ~4KB dirty at fence time (out comes later).
    s_end[(size_t)(chunk * BB + b) * (CC / 2) + tid] = make_float4(hr0, hi0, hr1, hi1);
    __threadfence();          // device-scope release of this thread's store
    __syncthreads();
    if (tid == 0)
        __hip_atomic_store(&flags[b * NCHUNK + chunk], FLAG_MAGIC,
                           __ATOMIC_RELEASE, __HIP_MEMORY_SCOPE_AGENT);

    // A^LCHUNK per channel (5 complex squarings) - overlaps with waiting.
    float p0r = a_r.x, p0i = a_i.x, p1r = a_r.y, p1i = a_i.y;
#pragma unroll
    for (int s = 0; s < 5; ++s) {
        float n0r = p0r * p0r - p0i * p0i, n0i = 2.f * p0r * p0i;
        float n1r = p1r * p1r - p1i * p1i, n1i = 2.f * p1r * p1i;
        p0r = n0r; p0i = n0i; p1r = n1r; p1i = n1i;
    }

    // Wait for predecessors: lane t polls flag[b][t] (distributed lines,
    // read-only sharing - no ping-pong). chunk <= 127 < 256 lanes.
    if (tid < chunk) {
        while (__hip_atomic_load(&flags[b * NCHUNK + tid], __ATOMIC_RELAXED,
                                 __HIP_MEMORY_SCOPE_AGENT) != FLAG_MAGIC) {}
    }
    __syncthreads();
    __builtin_amdgcn_fence(__ATOMIC_ACQUIRE, "agent");   // invalidate stale L1/L2

    // Chunk-start state: h = h0; for j<chunk: h = A^L*h + s_end[j][b].
    hr0 = h0rv.x; hr1 = h0rv.y; hi0 = h0iv.x; hi1 = h0iv.y;
    const float4* sp = s_end + tid;
#pragma unroll 4
    for (int j = 0; j < chunk; ++j) {
        float4 s = sp[(size_t)(j * BB + b) * (CC / 2)];
        float nr0 = p0r * hr0 - p0i * hi0 + s.x;
        float ni0 = p0i * hr0 + p0r * hi0 + s.y;
        float nr1 = p1r * hr1 - p1i * hi1 + s.z;
        float ni1 = p1i * hr1 + p1r * hi1 + s.w;
        hr0 = nr0; hi0 = ni0; hr1 = nr1; hi1 = ni1;
    }

    // Emit all 32 steps from register-staged x; streaming stores.
    floatx4* op = (floatx4*)(out + (size_t)(b * TT + t0) * (CC / 2) + tid);
#pragma unroll
    for (int t = 0; t < LCHUNK; ++t) {
        float2 xv = xs[t];
        float nr0 = fmaf(hr0, a_r.x, fmaf(-hi0, a_i.x, xv.x));
        float ni0 = fmaf(a_i.x, hr0, a_r.x * hi0);
        float nr1 = fmaf(hr1, a_r.y, fmaf(-hi1, a_i.y, xv.y));
        float ni1 = fmaf(a_i.y, hr1, a_r.y * hi1);
        hr0 = nr0; hi0 = ni0; hr1 = nr1; hi1 = ni1;
        floatx4 v = {nr0, ni0, nr1, ni1};
        __builtin_nontemporal_store(v, &op[(size_t)t * (CC / 2)]);
    }
}

extern "C" void kernel_launch(void* const* d_in, const int* in_sizes, int n_in,
                              void* d_out, int out_size, void* d_ws, size_t ws_size,
                              hipStream_t stream) {
    const float* x   = (const float*)d_in[0];
    const float* Ar  = (const float*)d_in[1];
    const float* Ai  = (const float*)d_in[2];
    const float* h0r = (const float*)d_in[3];
    const float* h0i = (const float*)d_in[4];

    float4* s_end = (float4*)d_ws;                          // 4 MiB
    unsigned int* flags = (unsigned int*)((char*)d_ws + (size_t)NCHUNK * BB * (CC / 2) * 16);
    // flags poisoned to 0xAAAAAAAA each call != FLAG_MAGIC -> self-initializing.

    rec_lookback<<<BB * NCHUNK, 256, 0, stream>>>(x, Ar, Ai, h0r, h0i,
                                                  s_end, flags, (float4*)d_out);
}

// Round 7
// 206.478 us; speedup vs baseline: 1.9521x; 1.9521x over previous
//
#include <hip/hip_runtime.h>

#define BB 8
#define TT 4096
#define CC 512
#define NCHUNK 128
#define LCHUNK (TT / NCHUNK)   // 32

typedef float floatx4 __attribute__((ext_vector_type(4)));

// Kernel 1: per-chunk local scan with zero initial state; store chunk-end
// state (float4 = 2 channels' r,i), layout [chunk][b][c/2]. HBM-bound x read.
__global__ __launch_bounds__(256, 4) void rec_ends(const float* __restrict__ x,
                                                   const float* __restrict__ Ar,
                                                   const float* __restrict__ Ai,
                                                   float4* __restrict__ s_end) {
    const int tid   = threadIdx.x;            // channels 2*tid, 2*tid+1
    const int blk   = blockIdx.x;
    const int b     = blk / NCHUNK;
    const int chunk = blk % NCHUNK;
    const int t0    = chunk * LCHUNK;

    const float2 a_r = ((const float2*)Ar)[tid];
    const float2 a_i = ((const float2*)Ai)[tid];
    const float2* xp = (const float2*)(x + (size_t)(b * TT + t0) * CC) + tid;

    float hr0 = 0.f, hi0 = 0.f, hr1 = 0.f, hi1 = 0.f;
#pragma unroll 8
    for (int t = 0; t < LCHUNK; ++t) {
        float2 xv = xp[(size_t)t * (CC / 2)];
        float nr0 = fmaf(hr0, a_r.x, fmaf(-hi0, a_i.x, xv.x));
        float ni0 = fmaf(a_i.x, hr0, a_r.x * hi0);
        float nr1 = fmaf(hr1, a_r.y, fmaf(-hi1, a_i.y, xv.y));
        float ni1 = fmaf(a_i.y, hr1, a_r.y * hi1);
        hr0 = nr0; hi0 = ni0; hr1 = nr1; hi1 = ni1;
    }
    s_end[(size_t)(chunk * BB + b) * (CC / 2) + tid] = make_float4(hr0, hi0, hr1, hi1);
}

// Kernel 2: stage x in registers (overlaps the prefix chain), compute own
// chunk-start via A^L prefix over earlier chunks' end-states (L2/L3-resident),
// then emit all 32 steps with nontemporal stores (out never pollutes L2).
__global__ __launch_bounds__(256, 4) void rec_emit(const float* __restrict__ x,
                                                   const float* __restrict__ Ar,
                                                   const float* __restrict__ Ai,
                                                   const float* __restrict__ h0r,
                                                   const float* __restrict__ h0i,
                                                   const float4* __restrict__ s_end,
                                                   float4* __restrict__ out) {
    const int tid   = threadIdx.x;
    const int blk   = blockIdx.x;
    const int b     = blk / NCHUNK;
    const int chunk = blk % NCHUNK;
    const int t0    = chunk * LCHUNK;

    const float2 a_r = ((const float2*)Ar)[tid];
    const float2 a_i = ((const float2*)Ai)[tid];

    // Issue x loads FIRST; they stay in flight while the prefix chain runs.
    const float2* xp = (const float2*)(x + (size_t)(b * TT + t0) * CC) + tid;
    float2 xs[LCHUNK];
#pragma unroll
    for (int t = 0; t < LCHUNK; ++t)
        xs[t] = xp[(size_t)t * (CC / 2)];

    // A^LCHUNK per channel (LCHUNK = 32 -> 5 complex squarings).
    float p0r = a_r.x, p0i = a_i.x, p1r = a_r.y, p1i = a_i.y;
#pragma unroll
    for (int s = 0; s < 5; ++s) {
        float n0r = p0r * p0r - p0i * p0i, n0i = 2.f * p0r * p0i;
        float n1r = p1r * p1r - p1i * p1i, n1i = 2.f * p1r * p1i;
        p0r = n0r; p0i = n0i; p1r = n1r; p1i = n1i;
    }

    // Chunk-start state: h = h0; for j<chunk: h = A^L*h + s_end[j].
    float2 h0rv = ((const float2*)(h0r + (size_t)b * CC))[tid];
    float2 h0iv = ((const float2*)(h0i + (size_t)b * CC))[tid];
    float hr0 = h0rv.x, hr1 = h0rv.y, hi0 = h0iv.x, hi1 = h0iv.y;

    const float4* sp = s_end + tid;
#pragma unroll 4
    for (int j = 0; j < chunk; ++j) {
        float4 s = sp[(size_t)(j * BB + b) * (CC / 2)];
        float nr0 = p0r * hr0 - p0i * hi0 + s.x;
        float ni0 = p0i * hr0 + p0r * hi0 + s.y;
        float nr1 = p1r * hr1 - p1i * hi1 + s.z;
        float ni1 = p1i * hr1 + p1r * hi1 + s.w;
        hr0 = nr0; hi0 = ni0; hr1 = nr1; hi1 = ni1;
    }

    // Emit all 32 steps from register-staged x; streaming stores.
    floatx4* op = (floatx4*)(out + (size_t)(b * TT + t0) * (CC / 2) + tid);
#pragma unroll
    for (int t = 0; t < LCHUNK; ++t) {
        float2 xv = xs[t];
        float nr0 = fmaf(hr0, a_r.x, fmaf(-hi0, a_i.x, xv.x));
        float ni0 = fmaf(a_i.x, hr0, a_r.x * hi0);
        float nr1 = fmaf(hr1, a_r.y, fmaf(-hi1, a_i.y, xv.y));
        float ni1 = fmaf(a_i.y, hr1, a_r.y * hi1);
        hr0 = nr0; hi0 = ni0; hr1 = nr1; hi1 = ni1;
        floatx4 v = {nr0, ni0, nr1, ni1};
        __builtin_nontemporal_store(v, &op[(size_t)t * (CC / 2)]);
    }
}

extern "C" void kernel_launch(void* const* d_in, const int* in_sizes, int n_in,
                              void* d_out, int out_size, void* d_ws, size_t ws_size,
                              hipStream_t stream) {
    const float* x   = (const float*)d_in[0];
    const float* Ar  = (const float*)d_in[1];
    const float* Ai  = (const float*)d_in[2];
    const float* h0r = (const float*)d_in[3];
    const float* h0i = (const float*)d_in[4];
    float4* s_end = (float4*)d_ws;          // NCHUNK*BB*(CC/2) float4 = 4 MiB

    rec_ends<<<BB * NCHUNK, 256, 0, stream>>>(x, Ar, Ai, s_end);
    rec_emit<<<BB * NCHUNK, 256, 0, stream>>>(x, Ar, Ai, h0r, h0i, s_end,
                                              (float4*)d_out);
}